// Round 4
// baseline (189.355 us; speedup 1.0000x reference)
//
#include <hip/hip_runtime.h>
#include <math.h>

typedef __attribute__((ext_vector_type(8))) short  short8;    // 8 bf16 = 4 VGPRs
typedef __attribute__((ext_vector_type(4))) float  floatx4;   // MFMA C/D

#define MFMA16(a, b, c) __builtin_amdgcn_mfma_f32_16x16x32_bf16(a, b, c, 0, 0, 0)

constexpr int NSEQ = 2048;
constexpr int DIN  = 768;
constexpr int NH   = 12;
constexpr size_t NX = (size_t)2 * NSEQ * DIN;   // x elems  = 3,145,728
constexpr size_t NW = (size_t)DIN * DIN;        // Wq elems =   589,824
constexpr float QSCALE = 0.18033688011112042f;  // log2(e)/8

__device__ __forceinline__ ushort f2bf(float f) {   // RNE fp32 -> bf16
    unsigned u = __float_as_uint(f);
    u += 0x7FFF + ((u >> 16) & 1);
    return (ushort)(u >> 16);
}
__device__ __forceinline__ float bf2f(ushort u) {
    return __uint_as_float(((unsigned)u) << 16);
}
__device__ __forceinline__ unsigned cvt_pk_bf16(float lo, float hi) {
    unsigned r;
    asm("v_cvt_pk_bf16_f32 %0, %1, %2" : "=v"(r) : "v"(lo), "v"(hi));
    return r;
}
// LDS-only barrier (qkv kernel): orders ds ops without draining vmcnt.
__device__ __forceinline__ void bar_lds() {
    asm volatile("s_waitcnt lgkmcnt(0)" ::: "memory");
    __builtin_amdgcn_s_barrier();
}

// -----------------------------------------------------------------------------
// Kernel 0: convert x and Wq to bf16 (contiguous in ws). Memory-bound, ~4 us.
// -----------------------------------------------------------------------------
__global__ __launch_bounds__(256)
void cvt_bf16(const float* __restrict__ x, const float* __restrict__ Wq,
              ushort* __restrict__ dst)
{
    size_t i = ((size_t)blockIdx.x * 256 + threadIdx.x) * 8;
    const float* s = (i < NX) ? (x + i) : (Wq + (i - NX));
    float4 f0 = ((const float4*)s)[0];
    float4 f1 = ((const float4*)s)[1];
    short8 o;
    o[0] = (short)f2bf(f0.x); o[1] = (short)f2bf(f0.y);
    o[2] = (short)f2bf(f0.z); o[3] = (short)f2bf(f0.w);
    o[4] = (short)f2bf(f1.x); o[5] = (short)f2bf(f1.y);
    o[6] = (short)f2bf(f1.z); o[7] = (short)f2bf(f1.w);
    *(short8*)(dst + i) = o;
}

// -----------------------------------------------------------------------------
// Kernel 1: h = xb @ wb^T. BM=64 x BN=64, grid (64,12) = 768 blocks, 3/CU.
// lgkmcnt-only barriers keep the register prefetch in flight (round-3 verified).
// -----------------------------------------------------------------------------
__global__ __launch_bounds__(256, 3)
void qkv_mfma(const ushort* __restrict__ xb, const ushort* __restrict__ wb,
              ushort* __restrict__ h)
{
    __shared__ ushort As[64 * 72];    // [row][k] pitch 72
    __shared__ ushort Bs[64 * 72];    // [col][k]

    const int tid  = threadIdx.x;
    const int w    = tid >> 6;
    const int lane = tid & 63;
    const int m    = lane & 15;
    const int quad = lane >> 4;
    const int r0   = blockIdx.x * 64;
    const int c0   = blockIdx.y * 64;
    const int mrow0 = (w & 1) * 32;
    const int ncol0 = (w >> 1) * 32;

    floatx4 C[2][2] = {};
    short8 ar[2], br[2];

    #pragma unroll
    for (int i = 0; i < 2; ++i) {
        int id = tid + i * 256;
        ar[i] = *(const short8*)(xb + (size_t)(r0 + (id >> 3)) * DIN + (id & 7) * 8);
        br[i] = *(const short8*)(wb + (size_t)(c0 + (id >> 3)) * DIN + (id & 7) * 8);
    }

    for (int kk = 0; kk < 12; ++kk) {
        bar_lds();
        #pragma unroll
        for (int i = 0; i < 2; ++i) {
            int id = tid + i * 256;
            *(short8*)&As[(id >> 3) * 72 + (id & 7) * 8] = ar[i];
            *(short8*)&Bs[(id >> 3) * 72 + (id & 7) * 8] = br[i];
        }
        if (kk < 11) {
            const int k0 = (kk + 1) * 64;
            #pragma unroll
            for (int i = 0; i < 2; ++i) {
                int id = tid + i * 256;
                ar[i] = *(const short8*)(xb + (size_t)(r0 + (id >> 3)) * DIN + k0 + (id & 7) * 8);
                br[i] = *(const short8*)(wb + (size_t)(c0 + (id >> 3)) * DIN + k0 + (id & 7) * 8);
            }
        }
        bar_lds();

        #pragma unroll
        for (int kt2 = 0; kt2 < 2; ++kt2) {
            short8 a0 = *(const short8*)&As[(mrow0 + m)      * 72 + kt2 * 32 + quad * 8];
            short8 a1 = *(const short8*)&As[(mrow0 + 16 + m) * 72 + kt2 * 32 + quad * 8];
            short8 b0 = *(const short8*)&Bs[(ncol0 + m)      * 72 + kt2 * 32 + quad * 8];
            short8 b1 = *(const short8*)&Bs[(ncol0 + 16 + m) * 72 + kt2 * 32 + quad * 8];
            C[0][0] = MFMA16(a0, b0, C[0][0]);
            C[0][1] = MFMA16(a0, b1, C[0][1]);
            C[1][0] = MFMA16(a1, b0, C[1][0]);
            C[1][1] = MFMA16(a1, b1, C[1][1]);
        }
    }

    #pragma unroll
    for (int mt = 0; mt < 2; ++mt)
        #pragma unroll
        for (int nt = 0; nt < 2; ++nt) {
            int cg = c0 + ncol0 + nt * 16 + m;
            int head = cg >> 6, d = cg & 63;
            #pragma unroll
            for (int r = 0; r < 4; ++r) {
                int rg = r0 + mrow0 + mt * 16 + quad * 4 + r;
                int b = rg >> 11, q = rg & 2047;
                h[((size_t)(b * NH + head) * NSEQ + q) * 64 + d] = f2bf(C[mt][nt][r]);
            }
        }
}

// -----------------------------------------------------------------------------
// Kernel 2: causal flash attention — BARRIER-FREE per-wave k-split.
// Block = 32 q rows, 2 waves, grid (64,24) = 1536 blocks = 6/CU = 12 waves/CU.
// Wave w processes k-tiles (32 keys each) kt = w, w+2, ... < qt+1, staging its
// OWN K/V^T into a private LDS region -> every LDS read is same-wave, ZERO
// s_barrier in the main loop (k-tiles commute: raw exp2, no running max).
// Partial O / l merged through LDS once at the end (2 barriers total).
// Pitches 66/34/33 (odd dwords) replace 72 -> kills the 8-way b128 conflicts.
// -----------------------------------------------------------------------------
__global__ __launch_bounds__(128, 3)
void attn_mfma(const ushort* __restrict__ h, float* __restrict__ out)
{
    __shared__ ushort sm[10752];        // 21504 B total, 5376 ushorts per wave

    const int tid  = threadIdx.x;
    const int w    = tid >> 6;          // 0..1
    const int lane = tid & 63;
    const int m    = lane & 15;
    const int quad = lane >> 4;

    const int xi = blockIdx.x;          // 0..63
    const int bh = blockIdx.y;          // 0..23
    const int qt = ((bh >> 2) & 1) ? xi : (63 - xi);  // per-CU heavy/light mix
    const int q0 = qt * 32;
    const int nkt = qt + 1;             // # of 32-key tiles
    const ushort* __restrict__ Hh = h + (size_t)bh * NSEQ * 64;

    ushort* Ks = sm + w * 5376;         // [32 keys][pitch 66]
    ushort* Vt = Ks + 32 * 66;          // [64 d][pitch 34]
    ushort* Ps = Vt + 64 * 34;          // [2 qsub][16 q][pitch 34]

    // Q fragments for BOTH 16-q subtiles (B-operand: n=q=m, k=d), pre-scaled
    short8 qa[2][2];
    #pragma unroll
    for (int s = 0; s < 2; ++s)
        #pragma unroll
        for (int kt2 = 0; kt2 < 2; ++kt2) {
            short8 raw = *(const short8*)(Hh + (size_t)(q0 + s * 16 + m) * 64 + kt2 * 32 + quad * 8);
            #pragma unroll
            for (int j = 0; j < 8; ++j)
                qa[s][kt2][j] = (short)f2bf(bf2f((ushort)raw[j]) * QSCALE);
        }

    floatx4 O[4][2] = {};               // [d-tile mt][qsub]: d=mt*16+quad*4+r, q=s*16+m
    float lacc[2] = {0.0f, 0.0f};

    const int kr2 = (lane & 15) * 2;    // this lane stages key rows kr2, kr2+1
    const int db  = quad * 16;          // d-chunk (16 wide)

    short8 pre[4];                      // [row0 d0-7][row0 d8-15][row1 d0-7][row1 d8-15]
    {
        const ushort* src = Hh + (size_t)(w * 32 + kr2) * 64 + db;
        pre[0] = *(const short8*)src;
        pre[1] = *(const short8*)(src + 8);
        pre[2] = *(const short8*)(src + 64);
        pre[3] = *(const short8*)(src + 72);
    }

    for (int kt = w; kt < nkt; kt += 2) {
        // ---- stage own K tile (32x64) + V^T, same-wave only, no barrier ----
        *(short8*)&Ks[kr2       * 66 + db]     = pre[0];
        *(short8*)&Ks[kr2       * 66 + db + 8] = pre[1];
        *(short8*)&Ks[(kr2 + 1) * 66 + db]     = pre[2];
        *(short8*)&Ks[(kr2 + 1) * 66 + db + 8] = pre[3];
        union { short8 v; ushort u[8]; } a0, a1, b0, b1;
        a0.v = pre[0]; a1.v = pre[1]; b0.v = pre[2]; b1.v = pre[3];
        #pragma unroll
        for (int i = 0; i < 8; ++i) {
            *(unsigned*)&Vt[(db + i)     * 34 + kr2] = (unsigned)a0.u[i] | ((unsigned)b0.u[i] << 16);
            *(unsigned*)&Vt[(db + 8 + i) * 34 + kr2] = (unsigned)a1.u[i] | ((unsigned)b1.u[i] << 16);
        }
        if (kt + 2 < nkt) {             // prefetch this wave's next tile
            const ushort* src = Hh + (size_t)((kt + 2) * 32 + kr2) * 64 + db;
            pre[0] = *(const short8*)src;
            pre[1] = *(const short8*)(src + 8);
            pre[2] = *(const short8*)(src + 64);
            pre[3] = *(const short8*)(src + 72);
        }

        // ---- S^T = K Q^T : 32 keys x 32 q (ka shared across both qsubs) ----
        floatx4 S[2][2] = {};           // [key-tile mt][qsub]
        #pragma unroll
        for (int kt2 = 0; kt2 < 2; ++kt2)
            #pragma unroll
            for (int mt = 0; mt < 2; ++mt) {
                short8 ka = *(const short8*)&Ks[(mt * 16 + m) * 66 + kt2 * 32 + quad * 8];
                S[mt][0] = MFMA16(ka, qa[0][kt2], S[mt][0]);
                S[mt][1] = MFMA16(ka, qa[1][kt2], S[mt][1]);
            }

        // ---- exp2 (+causal mask on diagonal tile) + packed P + l accum ----
        const bool diag = (kt == qt);
        #pragma unroll
        for (int s = 0; s < 2; ++s) {
            const int lim = s * 16 + m;          // in-tile causal limit
            #pragma unroll
            for (int mt = 0; mt < 2; ++mt) {
                const int kb = mt * 16 + quad * 4;
                float p0, p1, p2, p3;
                if (diag) {
                    p0 = (kb + 0 <= lim) ? exp2f(S[mt][s][0]) : 0.0f;
                    p1 = (kb + 1 <= lim) ? exp2f(S[mt][s][1]) : 0.0f;
                    p2 = (kb + 2 <= lim) ? exp2f(S[mt][s][2]) : 0.0f;
                    p3 = (kb + 3 <= lim) ? exp2f(S[mt][s][3]) : 0.0f;
                } else {
                    p0 = exp2f(S[mt][s][0]);
                    p1 = exp2f(S[mt][s][1]);
                    p2 = exp2f(S[mt][s][2]);
                    p3 = exp2f(S[mt][s][3]);
                }
                lacc[s] += (p0 + p1) + (p2 + p3);
                uint2 pw;
                pw.x = cvt_pk_bf16(p0, p1);
                pw.y = cvt_pk_bf16(p2, p3);
                *(uint2*)&Ps[s * 544 + m * 34 + kb] = pw;   // 544 = 16*34
            }
        }

        // ---- O^T += V^T P^T : k=32 keys in ONE MFMA per (d-tile, qsub) ----
        short8 pb0 = *(const short8*)&Ps[0 * 544 + m * 34 + quad * 8];
        short8 pb1 = *(const short8*)&Ps[1 * 544 + m * 34 + quad * 8];
        #pragma unroll
        for (int mt = 0; mt < 4; ++mt) {
            short8 va = *(const short8*)&Vt[(mt * 16 + m) * 34 + quad * 8];
            O[mt][0] = MFMA16(va, pb0, O[mt][0]);
            O[mt][1] = MFMA16(va, pb1, O[mt][1]);
        }
    }

    // ---- reduce l across quads (keys were spread over quad*4+r rows) ----
    #pragma unroll
    for (int s = 0; s < 2; ++s) {
        lacc[s] += __shfl_xor(lacc[s], 16);
        lacc[s] += __shfl_xor(lacc[s], 32);
    }

    // ---- merge the two waves' partial O / l through LDS ----
    __syncthreads();                    // both waves done with Ks/Vt/Ps
    float* OM = (float*)sm;             // [2][64][pitch 33] = 16896 B
    float* LM = (float*)sm + 2 * 64 * 33;   // [2][32]
    #pragma unroll
    for (int mt = 0; mt < 4; ++mt)
        #pragma unroll
        for (int s = 0; s < 2; ++s)
            #pragma unroll
            for (int r = 0; r < 4; ++r) {
                int d = mt * 16 + quad * 4 + r;
                OM[((size_t)w * 64 + d) * 33 + s * 16 + m] = O[mt][s][r];
            }
    if (quad == 0) {
        LM[w * 32 + 0 * 16 + m] = lacc[0];
        LM[w * 32 + 1 * 16 + m] = lacc[1];
    }
    __syncthreads();

    // wave w finalizes qsub s = w: add other wave's partials, scale, store
    const int ow = 1 - w;
    float lf = lacc[w] + LM[ow * 32 + w * 16 + m];
    float linv = 1.0f / lf;
    #pragma unroll
    for (int mt = 0; mt < 4; ++mt)
        #pragma unroll
        for (int r = 0; r < 4; ++r) {
            int d = mt * 16 + quad * 4 + r;
            float v = O[mt][w][r] + OM[((size_t)ow * 64 + d) * 33 + w * 16 + m];
            out[((size_t)bh * 64 + d) * NSEQ + q0 + w * 16 + m] = v * linv;
        }
}

extern "C" void kernel_launch(void* const* d_in, const int* in_sizes, int n_in,
                              void* d_out, int out_size, void* d_ws, size_t ws_size,
                              hipStream_t stream)
{
    (void)in_sizes; (void)n_in; (void)out_size; (void)ws_size;
    const float* x  = (const float*)d_in[0];
    const float* Wq = (const float*)d_in[1];
    float* out = (float*)d_out;

    ushort* xb = (ushort*)d_ws;                 // 6.29 MB
    ushort* wb = xb + NX;                       // 1.18 MB
    ushort* hb = wb + NW;                       // 6.29 MB  (ws is 256 MiB)

    cvt_bf16<<<dim3((NX + NW) / (8 * 256)), dim3(256), 0, stream>>>(x, Wq, xb);
    qkv_mfma<<<dim3(64, 12), dim3(256), 0, stream>>>(xb, wb, hb);
    attn_mfma<<<dim3(64, 24), dim3(128), 0, stream>>>(hb, out);
}

// Round 5
// 152.829 us; speedup vs baseline: 1.2390x; 1.2390x over previous
//
#include <hip/hip_runtime.h>
#include <math.h>

typedef __attribute__((ext_vector_type(8))) short  short8;    // 8 bf16 = 4 VGPRs
typedef __attribute__((ext_vector_type(4))) float  floatx4;   // MFMA C/D

#define MFMA16(a, b, c) __builtin_amdgcn_mfma_f32_16x16x32_bf16(a, b, c, 0, 0, 0)

constexpr int NSEQ = 2048;
constexpr int DIN  = 768;
constexpr int NH   = 12;
constexpr size_t NX = (size_t)2 * NSEQ * DIN;   // x elems  = 3,145,728
constexpr size_t NW = (size_t)DIN * DIN;        // Wq elems =   589,824
constexpr float QSCALE = 0.18033688011112042f;  // log2(e)/8

// LDS pitches: 66 shorts = 33 dwords == 1 (mod 32)  -> row-rotated banks,
// kills the 8-way (stage write) / 4-way (fragment read) conflicts of pitch 72.
constexpr int PK = 66;

__device__ __forceinline__ ushort f2bf(float f) {   // RNE fp32 -> bf16
    unsigned u = __float_as_uint(f);
    u += 0x7FFF + ((u >> 16) & 1);
    return (ushort)(u >> 16);
}
__device__ __forceinline__ float bf2f(ushort u) {
    return __uint_as_float(((unsigned)u) << 16);
}
__device__ __forceinline__ unsigned cvt_pk_bf16(float lo, float hi) {
    unsigned r;
    asm("v_cvt_pk_bf16_f32 %0, %1, %2" : "=v"(r) : "v"(lo), "v"(hi));
    return r;
}
// LDS-only barrier: orders ds ops across the block WITHOUT draining vmcnt,
// so register prefetch loads stay in flight across the barrier.
__device__ __forceinline__ void bar_lds() {
    asm volatile("s_waitcnt lgkmcnt(0)" ::: "memory");
    __builtin_amdgcn_s_barrier();
}

// -----------------------------------------------------------------------------
// Kernel 0: convert x and Wq to bf16 (contiguous in ws). Memory-bound, ~4 us.
// -----------------------------------------------------------------------------
__global__ __launch_bounds__(256)
void cvt_bf16(const float* __restrict__ x, const float* __restrict__ Wq,
              ushort* __restrict__ dst)
{
    size_t i = ((size_t)blockIdx.x * 256 + threadIdx.x) * 8;
    const float* s = (i < NX) ? (x + i) : (Wq + (i - NX));
    float4 f0 = ((const float4*)s)[0];
    float4 f1 = ((const float4*)s)[1];
    short8 o;
    o[0] = (short)f2bf(f0.x); o[1] = (short)f2bf(f0.y);
    o[2] = (short)f2bf(f0.z); o[3] = (short)f2bf(f0.w);
    o[4] = (short)f2bf(f1.x); o[5] = (short)f2bf(f1.y);
    o[6] = (short)f2bf(f1.z); o[7] = (short)f2bf(f1.w);
    *(short8*)(dst + i) = o;
}

// -----------------------------------------------------------------------------
// Kernel 1: h = xb @ wb^T. BM=64 x BN=64, grid (64,12) = 768 blocks, 3/CU.
// Round-3 verified structure; only change: pitch 72 -> 66 (bank-conflict fix).
// -----------------------------------------------------------------------------
__global__ __launch_bounds__(256, 3)
void qkv_mfma(const ushort* __restrict__ xb, const ushort* __restrict__ wb,
              ushort* __restrict__ h)
{
    __shared__ ushort As[64 * PK];    // [row][k]
    __shared__ ushort Bs[64 * PK];    // [col][k]

    const int tid  = threadIdx.x;
    const int w    = tid >> 6;
    const int lane = tid & 63;
    const int m    = lane & 15;
    const int quad = lane >> 4;
    const int r0   = blockIdx.x * 64;
    const int c0   = blockIdx.y * 64;
    const int mrow0 = (w & 1) * 32;
    const int ncol0 = (w >> 1) * 32;

    floatx4 C[2][2] = {};
    short8 ar[2], br[2];

    #pragma unroll
    for (int i = 0; i < 2; ++i) {
        int id = tid + i * 256;
        ar[i] = *(const short8*)(xb + (size_t)(r0 + (id >> 3)) * DIN + (id & 7) * 8);
        br[i] = *(const short8*)(wb + (size_t)(c0 + (id >> 3)) * DIN + (id & 7) * 8);
    }

    for (int kk = 0; kk < 12; ++kk) {
        bar_lds();                      // prior reads consumed; no vmcnt drain
        #pragma unroll
        for (int i = 0; i < 2; ++i) {
            int id = tid + i * 256;
            *(short8*)&As[(id >> 3) * PK + (id & 7) * 8] = ar[i];
            *(short8*)&Bs[(id >> 3) * PK + (id & 7) * 8] = br[i];
        }
        if (kk < 11) {                  // prefetch next tile (stays in flight)
            const int k0 = (kk + 1) * 64;
            #pragma unroll
            for (int i = 0; i < 2; ++i) {
                int id = tid + i * 256;
                ar[i] = *(const short8*)(xb + (size_t)(r0 + (id >> 3)) * DIN + k0 + (id & 7) * 8);
                br[i] = *(const short8*)(wb + (size_t)(c0 + (id >> 3)) * DIN + k0 + (id & 7) * 8);
            }
        }
        bar_lds();                      // writes visible; loads NOT drained

        #pragma unroll
        for (int kt2 = 0; kt2 < 2; ++kt2) {
            short8 a0 = *(const short8*)&As[(mrow0 + m)      * PK + kt2 * 32 + quad * 8];
            short8 a1 = *(const short8*)&As[(mrow0 + 16 + m) * PK + kt2 * 32 + quad * 8];
            short8 b0 = *(const short8*)&Bs[(ncol0 + m)      * PK + kt2 * 32 + quad * 8];
            short8 b1 = *(const short8*)&Bs[(ncol0 + 16 + m) * PK + kt2 * 32 + quad * 8];
            C[0][0] = MFMA16(a0, b0, C[0][0]);
            C[0][1] = MFMA16(a0, b1, C[0][1]);
            C[1][0] = MFMA16(a1, b0, C[1][0]);
            C[1][1] = MFMA16(a1, b1, C[1][1]);
        }
    }

    #pragma unroll
    for (int mt = 0; mt < 2; ++mt)
        #pragma unroll
        for (int nt = 0; nt < 2; ++nt) {
            int cg = c0 + ncol0 + nt * 16 + m;
            int head = cg >> 6, d = cg & 63;
            #pragma unroll
            for (int r = 0; r < 4; ++r) {
                int rg = r0 + mrow0 + mt * 16 + quad * 4 + r;
                int b = rg >> 11, q = rg & 2047;
                h[((size_t)(b * NH + head) * NSEQ + q) * 64 + d] = f2bf(C[mt][nt][r]);
            }
        }
}

// -----------------------------------------------------------------------------
// Kernel 2: causal flash attention (round-3 verified structure + pitch fix).
// Block = 2 waves x 16 q; each block owns the complementary q-tile PAIR
// (qt, 63-qt): k-tile counts sum to EXACTLY 33 -> all 768 blocks (grid 32x24,
// 3/CU) do identical work under any dispatch order. Cooperative 64-key K/V^T
// staging + bar_lds barriers (no vmcnt drain). Pitch 66 (odd dwords) kills the
// pitch-72 bank conflicts (round-4 measured: 6.1M -> 0.3M conflict cycles).
// __launch_bounds__(128,2): VGPR cap 256 (was 64) for scheduler headroom.
// -----------------------------------------------------------------------------
__global__ __launch_bounds__(128, 2)
void attn_mfma(const ushort* __restrict__ h, float* __restrict__ out)
{
    __shared__ ushort Ks[64 * PK];      // [key][d]
    __shared__ ushort Vt[64 * PK];      // [d][key]
    __shared__ ushort Ps[2 * 16 * PK];  // per-wave P [q][key]

    const int tid  = threadIdx.x;
    const int w    = tid >> 6;          // 0..1
    const int lane = tid & 63;
    const int m    = lane & 15;
    const int quad = lane >> 4;

    const int p  = blockIdx.x;          // pair id 0..31
    const int bh = blockIdx.y;          // 0..23
    const ushort* __restrict__ Hh = h + (size_t)bh * NSEQ * 64;
    ushort* Psw = Ps + w * 16 * PK;

    const int kr2  = (tid & 31) * 2;    // staging: 2 adjacent key rows
    const int part = tid >> 5;          // d-chunk 0..3 (16 d each)
    const int db   = part * 16;

    #pragma unroll 1
    for (int half = 0; half < 2; ++half) {
        const int qt  = half ? p : (63 - p);
        const int q0  = qt * 32;
        const int wq  = q0 + w * 16;    // this wave's q base
        const int nkt = (qt >> 1) + 1;  // # of 64-key tiles

        // Q fragments (B-operand: n=q=m, k=d), pre-scaled by log2(e)/8
        short8 qa[2];
        #pragma unroll
        for (int kt2 = 0; kt2 < 2; ++kt2) {
            short8 raw = *(const short8*)(Hh + (size_t)(wq + m) * 64 + kt2 * 32 + quad * 8);
            #pragma unroll
            for (int j = 0; j < 8; ++j)
                qa[kt2][j] = (short)f2bf(bf2f((ushort)raw[j]) * QSCALE);
        }

        floatx4 O[4] = {};              // O^T tiles: d = mt*16+quad*4+r, q = m
        float lacc = 0.0f;

        short8 pre[4];                  // prefetched K rows kr2, kr2+1
        {
            const ushort* src = Hh + (size_t)kr2 * 64 + db;
            pre[0] = *(const short8*)src;
            pre[1] = *(const short8*)(src + 8);
            pre[2] = *(const short8*)(src + 64);
            pre[3] = *(const short8*)(src + 72);
        }

        for (int kt = 0; kt < nkt; ++kt) {
            bar_lds();                  // Ks/Vt free for overwrite (no vmcnt drain)
            *(short8*)&Ks[kr2       * PK + db]     = pre[0];
            *(short8*)&Ks[kr2       * PK + db + 8] = pre[1];
            *(short8*)&Ks[(kr2 + 1) * PK + db]     = pre[2];
            *(short8*)&Ks[(kr2 + 1) * PK + db + 8] = pre[3];
            union { short8 v; ushort u[8]; } a0, a1, b0, b1;
            a0.v = pre[0]; a1.v = pre[1]; b0.v = pre[2]; b1.v = pre[3];
            #pragma unroll
            for (int i = 0; i < 8; ++i) {
                *(unsigned*)&Vt[(db + i)     * PK + kr2] = (unsigned)a0.u[i] | ((unsigned)b0.u[i] << 16);
                *(unsigned*)&Vt[(db + 8 + i) * PK + kr2] = (unsigned)a1.u[i] | ((unsigned)b1.u[i] << 16);
            }
            if (kt + 1 < nkt) {         // prefetch next K tile (stays in flight)
                const ushort* src = Hh + (size_t)((kt + 1) * 64 + kr2) * 64 + db;
                pre[0] = *(const short8*)src;
                pre[1] = *(const short8*)(src + 8);
                pre[2] = *(const short8*)(src + 64);
                pre[3] = *(const short8*)(src + 72);
            }
            bar_lds();

            // ---- S^T = K Q^T : rows=key, cols=q ----
            floatx4 S[4] = {};
            #pragma unroll
            for (int kt2 = 0; kt2 < 2; ++kt2)
                #pragma unroll
                for (int mt = 0; mt < 4; ++mt) {
                    short8 ka = *(const short8*)&Ks[(mt * 16 + m) * PK + kt2 * 32 + quad * 8];
                    S[mt] = MFMA16(ka, qa[kt2], S[mt]);
                }

            // ---- exp2 + packed P write (cvt_pk) + l accumulate ----
            const int lim = wq + m - kt * 64;   // causal limit in-tile
            if (kt == nkt - 1) {                // diagonal tile: causal mask
                #pragma unroll
                for (int mt = 0; mt < 4; ++mt) {
                    float p0 = (mt * 16 + quad * 4 + 0 <= lim) ? exp2f(S[mt][0]) : 0.0f;
                    float p1 = (mt * 16 + quad * 4 + 1 <= lim) ? exp2f(S[mt][1]) : 0.0f;
                    float p2 = (mt * 16 + quad * 4 + 2 <= lim) ? exp2f(S[mt][2]) : 0.0f;
                    float p3 = (mt * 16 + quad * 4 + 3 <= lim) ? exp2f(S[mt][3]) : 0.0f;
                    lacc += (p0 + p1) + (p2 + p3);
                    uint2 pw;
                    pw.x = cvt_pk_bf16(p0, p1);
                    pw.y = cvt_pk_bf16(p2, p3);
                    *(uint2*)&Psw[m * PK + mt * 16 + quad * 4] = pw;
                }
            } else {                            // interior tile: no mask
                #pragma unroll
                for (int mt = 0; mt < 4; ++mt) {
                    float p0 = exp2f(S[mt][0]);
                    float p1 = exp2f(S[mt][1]);
                    float p2 = exp2f(S[mt][2]);
                    float p3 = exp2f(S[mt][3]);
                    lacc += (p0 + p1) + (p2 + p3);
                    uint2 pw;
                    pw.x = cvt_pk_bf16(p0, p1);
                    pw.y = cvt_pk_bf16(p2, p3);
                    *(uint2*)&Psw[m * PK + mt * 16 + quad * 4] = pw;
                }
            }

            // ---- O^T += V^T P^T (same-wave LDS, no barrier needed) ----
            #pragma unroll
            for (int kt2 = 0; kt2 < 2; ++kt2) {
                short8 pb = *(const short8*)&Psw[m * PK + kt2 * 32 + quad * 8];
                #pragma unroll
                for (int mt = 0; mt < 4; ++mt) {
                    short8 va = *(const short8*)&Vt[(mt * 16 + m) * PK + kt2 * 32 + quad * 8];
                    O[mt] = MFMA16(va, pb, O[mt]);
                }
            }
        }

        // ---- l reduce across the 4 quads holding the same q ----
        lacc += __shfl_xor(lacc, 16);
        lacc += __shfl_xor(lacc, 32);
        float linv = 1.0f / lacc;

        // ---- store out[bh][d][q] (reference's transposed layout) ----
        #pragma unroll
        for (int mt = 0; mt < 4; ++mt)
            #pragma unroll
            for (int r = 0; r < 4; ++r) {
                int d = mt * 16 + quad * 4 + r;
                out[((size_t)bh * 64 + d) * NSEQ + q0 + w * 16 + m] = O[mt][r] * linv;
            }
    }
}

extern "C" void kernel_launch(void* const* d_in, const int* in_sizes, int n_in,
                              void* d_out, int out_size, void* d_ws, size_t ws_size,
                              hipStream_t stream)
{
    (void)in_sizes; (void)n_in; (void)out_size; (void)ws_size;
    const float* x  = (const float*)d_in[0];
    const float* Wq = (const float*)d_in[1];
    float* out = (float*)d_out;

    ushort* xb = (ushort*)d_ws;                 // 6.29 MB
    ushort* wb = xb + NX;                       // 1.18 MB
    ushort* hb = wb + NW;                       // 6.29 MB  (ws is 256 MiB)

    cvt_bf16<<<dim3((NX + NW) / (8 * 256)), dim3(256), 0, stream>>>(x, Wq, xb);
    qkv_mfma<<<dim3(64, 12), dim3(256), 0, stream>>>(xb, wb, hb);
    attn_mfma<<<dim3(32, 24), dim3(128), 0, stream>>>(hb, out);
}

// Round 6
// 146.338 us; speedup vs baseline: 1.2940x; 1.0444x over previous
//
#include <hip/hip_runtime.h>
#include <math.h>

typedef __attribute__((ext_vector_type(8))) short  short8;    // 8 bf16 = 4 VGPRs
typedef __attribute__((ext_vector_type(4))) float  floatx4;   // MFMA C/D

#define MFMA16(a, b, c) __builtin_amdgcn_mfma_f32_16x16x32_bf16(a, b, c, 0, 0, 0)

constexpr int NSEQ = 2048;
constexpr int DIN  = 768;
constexpr int NH   = 12;
constexpr float QSCALE = 0.18033688011112042f;  // log2(e)/8

// Pitch 72 shorts = 144 B rows: keeps 16 B alignment for b128 ops (pitch 66's
// 132 B rows broke alignment -> round-5 regression). 36 dwords == 4 mod 32.
constexpr int PK = 72;

__device__ __forceinline__ ushort f2bf(float f) {   // RNE fp32 -> bf16
    unsigned u = __float_as_uint(f);
    u += 0x7FFF + ((u >> 16) & 1);
    return (ushort)(u >> 16);
}
__device__ __forceinline__ float bf2f(ushort u) {
    return __uint_as_float(((unsigned)u) << 16);
}
__device__ __forceinline__ unsigned cvt_pk_bf16(float lo, float hi) {
    unsigned r;
    asm("v_cvt_pk_bf16_f32 %0, %1, %2" : "=v"(r) : "v"(lo), "v"(hi));
    return r;
}
// pack 8 f32 -> 8 bf16 (RNE) with 4 instructions
__device__ __forceinline__ short8 pk8(float4 a, float4 b) {
    union { unsigned u[4]; short8 s; } r;
    r.u[0] = cvt_pk_bf16(a.x, a.y);
    r.u[1] = cvt_pk_bf16(a.z, a.w);
    r.u[2] = cvt_pk_bf16(b.x, b.y);
    r.u[3] = cvt_pk_bf16(b.z, b.w);
    return r.s;
}
// LDS-only barrier: orders ds ops across the block WITHOUT draining vmcnt,
// so register-prefetch global loads stay in flight across the barrier.
__device__ __forceinline__ void bar_lds() {
    asm volatile("s_waitcnt lgkmcnt(0)" ::: "memory");
    __builtin_amdgcn_s_barrier();
}

// -----------------------------------------------------------------------------
// Kernel 1: h = x @ Wq^T with FUSED f32->bf16 conversion (kernel 0 removed).
// BM=64 x BN=64, grid (64,12) = 768 blocks, 3/CU. Staging loads are f32
// float4 pairs, converted via v_cvt_pk_bf16_f32 at LDS-write time.
// lgkmcnt-only barriers keep the register prefetch in flight (round-3 verified).
// -----------------------------------------------------------------------------
__global__ __launch_bounds__(256, 3)
void qkv_mfma(const float* __restrict__ x, const float* __restrict__ Wq,
              ushort* __restrict__ h)
{
    __shared__ ushort As[64 * PK];    // [row][k]
    __shared__ ushort Bs[64 * PK];    // [col][k]

    const int tid  = threadIdx.x;
    const int w    = tid >> 6;
    const int lane = tid & 63;
    const int m    = lane & 15;
    const int quad = lane >> 4;
    const int r0   = blockIdx.x * 64;
    const int c0   = blockIdx.y * 64;
    const int mrow0 = (w & 1) * 32;
    const int ncol0 = (w >> 1) * 32;

    floatx4 C[2][2] = {};
    float4 arf[2][2], brf[2][2];      // f32 prefetch (8 floats per id)

    #pragma unroll
    for (int i = 0; i < 2; ++i) {
        int id = tid + i * 256;
        const float* ax = x  + (size_t)(r0 + (id >> 3)) * DIN + (id & 7) * 8;
        const float* bx = Wq + (size_t)(c0 + (id >> 3)) * DIN + (id & 7) * 8;
        arf[i][0] = ((const float4*)ax)[0]; arf[i][1] = ((const float4*)ax)[1];
        brf[i][0] = ((const float4*)bx)[0]; brf[i][1] = ((const float4*)bx)[1];
    }

    for (int kk = 0; kk < 12; ++kk) {
        bar_lds();                      // prior reads consumed; no vmcnt drain
        #pragma unroll
        for (int i = 0; i < 2; ++i) {
            int id = tid + i * 256;
            *(short8*)&As[(id >> 3) * PK + (id & 7) * 8] = pk8(arf[i][0], arf[i][1]);
            *(short8*)&Bs[(id >> 3) * PK + (id & 7) * 8] = pk8(brf[i][0], brf[i][1]);
        }
        if (kk < 11) {                  // prefetch next tile (stays in flight)
            const int k0 = (kk + 1) * 64;
            #pragma unroll
            for (int i = 0; i < 2; ++i) {
                int id = tid + i * 256;
                const float* ax = x  + (size_t)(r0 + (id >> 3)) * DIN + k0 + (id & 7) * 8;
                const float* bx = Wq + (size_t)(c0 + (id >> 3)) * DIN + k0 + (id & 7) * 8;
                arf[i][0] = ((const float4*)ax)[0]; arf[i][1] = ((const float4*)ax)[1];
                brf[i][0] = ((const float4*)bx)[0]; brf[i][1] = ((const float4*)bx)[1];
            }
        }
        bar_lds();                      // writes visible; loads NOT drained

        #pragma unroll
        for (int kt2 = 0; kt2 < 2; ++kt2) {
            short8 a0 = *(const short8*)&As[(mrow0 + m)      * PK + kt2 * 32 + quad * 8];
            short8 a1 = *(const short8*)&As[(mrow0 + 16 + m) * PK + kt2 * 32 + quad * 8];
            short8 b0 = *(const short8*)&Bs[(ncol0 + m)      * PK + kt2 * 32 + quad * 8];
            short8 b1 = *(const short8*)&Bs[(ncol0 + 16 + m) * PK + kt2 * 32 + quad * 8];
            C[0][0] = MFMA16(a0, b0, C[0][0]);
            C[0][1] = MFMA16(a0, b1, C[0][1]);
            C[1][0] = MFMA16(a1, b0, C[1][0]);
            C[1][1] = MFMA16(a1, b1, C[1][1]);
        }
    }

    #pragma unroll
    for (int mt = 0; mt < 2; ++mt)
        #pragma unroll
        for (int nt = 0; nt < 2; ++nt) {
            int cg = c0 + ncol0 + nt * 16 + m;
            int head = cg >> 6, d = cg & 63;
            #pragma unroll
            for (int r = 0; r < 4; ++r) {
                int rg = r0 + mrow0 + mt * 16 + quad * 4 + r;
                int b = rg >> 11, q = rg & 2047;
                h[((size_t)(b * NH + head) * NSEQ + q) * 64 + d] = f2bf(C[mt][nt][r]);
            }
        }
}

// -----------------------------------------------------------------------------
// Kernel 2: causal flash attention, K read DIRECTLY FROM GLOBAL (L2-resident:
// K/V per head = 256 KB; staging it in LDS was pure overhead — guide CM#7).
// Only V^T (transpose needed for PV) + per-wave P stay in LDS -> LDS/block
// 13.8 KB, Ks stage-write and the 8-way-conflicted Ks reads are gone, and
// S-MFMA issues BEFORE the barrier so Vt staging overlaps S compute.
// Block = 2 waves x 16 q; block owns complementary pair (qt, 63-qt): exactly
// 33 k-tile units for every block (grid 32x24 = 768 blocks, balanced).
// -----------------------------------------------------------------------------
__global__ __launch_bounds__(128, 3)
void attn_mfma(const ushort* __restrict__ h, float* __restrict__ out)
{
    __shared__ ushort Vt[64 * PK];      // [d][key]
    __shared__ ushort Ps[2 * 16 * PK];  // per-wave P [q][key]

    const int tid  = threadIdx.x;
    const int w    = tid >> 6;          // 0..1
    const int lane = tid & 63;
    const int m    = lane & 15;
    const int quad = lane >> 4;

    const int p  = blockIdx.x;          // pair id 0..31
    const int bh = blockIdx.y;          // 0..23
    const ushort* __restrict__ Hh = h + (size_t)bh * NSEQ * 64;
    ushort* Psw = Ps + w * 16 * PK;

    const int kr2  = (tid & 31) * 2;    // V staging: 2 adjacent key rows
    const int part = tid >> 5;          // d-chunk 0..3 (16 d each)
    const int db   = part * 16;

    #pragma unroll 1
    for (int half = 0; half < 2; ++half) {
        const int qt  = half ? p : (63 - p);
        const int q0  = qt * 32;
        const int wq  = q0 + w * 16;    // this wave's q base
        const int nkt = (qt >> 1) + 1;  // # of 64-key tiles

        // Q fragments (B-operand: n=q=m, k=d), pre-scaled by log2(e)/8
        short8 qa[2];
        #pragma unroll
        for (int kt2 = 0; kt2 < 2; ++kt2) {
            short8 raw = *(const short8*)(Hh + (size_t)(wq + m) * 64 + kt2 * 32 + quad * 8);
            #pragma unroll
            for (int j = 0; j < 8; ++j)
                qa[kt2][j] = (short)f2bf(bf2f((ushort)raw[j]) * QSCALE);
        }

        floatx4 O[4] = {};              // O^T tiles: d = mt*16+quad*4+r, q = m
        float lacc = 0.0f;

        short8 pre[4];                  // prefetched V rows kr2, kr2+1
        {
            const ushort* src = Hh + (size_t)kr2 * 64 + db;
            pre[0] = *(const short8*)src;
            pre[1] = *(const short8*)(src + 8);
            pre[2] = *(const short8*)(src + 64);
            pre[3] = *(const short8*)(src + 72);
        }

        for (int kt = 0; kt < nkt; ++kt) {
            // ---- S^T = K Q^T, K fragments straight from global (L2 hit) ----
            floatx4 S[4] = {};
            const ushort* Kg = Hh + (size_t)kt * 64 * 64;
            #pragma unroll
            for (int kt2 = 0; kt2 < 2; ++kt2)
                #pragma unroll
                for (int mt = 0; mt < 4; ++mt) {
                    short8 ka = *(const short8*)(Kg + (size_t)(mt * 16 + m) * 64 + kt2 * 32 + quad * 8);
                    S[mt] = MFMA16(ka, qa[kt2], S[mt]);
                }

            bar_lds();                  // prev-iter PV done reading Vt

            // ---- stage V^T (packed key-pairs per dword) ----
            union { short8 v; ushort u[8]; } a0, a1, b0, b1;
            a0.v = pre[0]; a1.v = pre[1]; b0.v = pre[2]; b1.v = pre[3];
            #pragma unroll
            for (int i = 0; i < 8; ++i) {
                *(unsigned*)&Vt[(db + i)     * PK + kr2] = (unsigned)a0.u[i] | ((unsigned)b0.u[i] << 16);
                *(unsigned*)&Vt[(db + 8 + i) * PK + kr2] = (unsigned)a1.u[i] | ((unsigned)b1.u[i] << 16);
            }
            if (kt + 1 < nkt) {         // prefetch next V tile (stays in flight)
                const ushort* src = Hh + (size_t)((kt + 1) * 64 + kr2) * 64 + db;
                pre[0] = *(const short8*)src;
                pre[1] = *(const short8*)(src + 8);
                pre[2] = *(const short8*)(src + 64);
                pre[3] = *(const short8*)(src + 72);
            }

            // ---- exp2 + packed P write (cvt_pk) + l accumulate ----
            const int lim = wq + m - kt * 64;   // causal limit in-tile
            if (kt == nkt - 1) {                // diagonal tile: causal mask
                #pragma unroll
                for (int mt = 0; mt < 4; ++mt) {
                    float p0 = (mt * 16 + quad * 4 + 0 <= lim) ? exp2f(S[mt][0]) : 0.0f;
                    float p1 = (mt * 16 + quad * 4 + 1 <= lim) ? exp2f(S[mt][1]) : 0.0f;
                    float p2 = (mt * 16 + quad * 4 + 2 <= lim) ? exp2f(S[mt][2]) : 0.0f;
                    float p3 = (mt * 16 + quad * 4 + 3 <= lim) ? exp2f(S[mt][3]) : 0.0f;
                    lacc += (p0 + p1) + (p2 + p3);
                    uint2 pw;
                    pw.x = cvt_pk_bf16(p0, p1);
                    pw.y = cvt_pk_bf16(p2, p3);
                    *(uint2*)&Psw[m * PK + mt * 16 + quad * 4] = pw;
                }
            } else {                            // interior tile: no mask
                #pragma unroll
                for (int mt = 0; mt < 4; ++mt) {
                    float p0 = exp2f(S[mt][0]);
                    float p1 = exp2f(S[mt][1]);
                    float p2 = exp2f(S[mt][2]);
                    float p3 = exp2f(S[mt][3]);
                    lacc += (p0 + p1) + (p2 + p3);
                    uint2 pw;
                    pw.x = cvt_pk_bf16(p0, p1);
                    pw.y = cvt_pk_bf16(p2, p3);
                    *(uint2*)&Psw[m * PK + mt * 16 + quad * 4] = pw;
                }
            }

            bar_lds();                  // Vt writes visible to both waves

            // ---- O^T += V^T P^T (Vt cross-wave, Ps same-wave) ----
            #pragma unroll
            for (int kt2 = 0; kt2 < 2; ++kt2) {
                short8 pb = *(const short8*)&Psw[m * PK + kt2 * 32 + quad * 8];
                #pragma unroll
                for (int mt = 0; mt < 4; ++mt) {
                    short8 va = *(const short8*)&Vt[(mt * 16 + m) * PK + kt2 * 32 + quad * 8];
                    O[mt] = MFMA16(va, pb, O[mt]);
                }
            }
        }

        // ---- l reduce across the 4 quads holding the same q ----
        lacc += __shfl_xor(lacc, 16);
        lacc += __shfl_xor(lacc, 32);
        float linv = 1.0f / lacc;

        // ---- store out[bh][d][q] (reference's transposed layout) ----
        #pragma unroll
        for (int mt = 0; mt < 4; ++mt)
            #pragma unroll
            for (int r = 0; r < 4; ++r) {
                int d = mt * 16 + quad * 4 + r;
                out[((size_t)bh * 64 + d) * NSEQ + q0 + w * 16 + m] = O[mt][r] * linv;
            }
    }
}

extern "C" void kernel_launch(void* const* d_in, const int* in_sizes, int n_in,
                              void* d_out, int out_size, void* d_ws, size_t ws_size,
                              hipStream_t stream)
{
    (void)in_sizes; (void)n_in; (void)out_size; (void)ws_size;
    const float* x  = (const float*)d_in[0];
    const float* Wq = (const float*)d_in[1];
    float* out = (float*)d_out;

    ushort* hb = (ushort*)d_ws;                 // 6.29 MB (ws is 256 MiB)

    qkv_mfma<<<dim3(64, 12), dim3(256), 0, stream>>>(x, Wq, hb);
    attn_mfma<<<dim3(32, 24), dim3(128), 0, stream>>>(hb, out);
}